// Round 7
// baseline (677.655 us; speedup 1.0000x reference)
//
#include <hip/hip_runtime.h>

// ---------------- problem constants ----------------
#define NNODES 100000
#define NEDGES 1600000
#define KDIM 256          // IN
#define CDIM 256          // H*F
#define NHEAD 4
#define FDIM 64
#define NEG 0.05f

typedef short bf16x8 __attribute__((ext_vector_type(8)));   // 8 bf16 in 4 VGPRs
typedef float f32x4  __attribute__((ext_vector_type(4)));
typedef __attribute__((address_space(3))) void*       lds_vp;
typedef __attribute__((address_space(1))) const void* glb_cvp;

__device__ __forceinline__ unsigned short f2b(float x) {   // fp32 -> bf16 RNE
    unsigned int u = __float_as_uint(x);
    return (unsigned short)((u + 0x7FFFu + ((u >> 16) & 1u)) >> 16);
}
__device__ __forceinline__ float b2f(unsigned short b) {
    return __uint_as_float(((unsigned int)b) << 16);
}
__device__ __forceinline__ float lrelu(float x) { return x > 0.f ? x : NEG * x; }

// monotone float<->uint mapping for atomicMax on signed floats
__device__ __forceinline__ unsigned int fmap(float f) {
    unsigned int u = __float_as_uint(f);
    return u ^ ((u >> 31) ? 0xFFFFFFFFu : 0x80000000u);
}
__device__ __forceinline__ float funmap(unsigned int u) {
    return __uint_as_float(u ^ ((u & 0x80000000u) ? 0x80000000u : 0xFFFFFFFFu));
}

// ---------------- fp32 -> bf16 convert + fused edge count ----------------
// Count atomics hit pad[dst*16]: ONE counter per 64B cache line -> no
// same-line RMW serialization at the L2 slices (the R7 experiment).
__global__ __launch_bounds__(256) void cvt_feat_count(
    const float* __restrict__ in, unsigned short* __restrict__ out,
    const int* __restrict__ dst, int* __restrict__ pad)
{
    int i = (blockIdx.x * 256 + threadIdx.x) * 4;
    float4 v = *(const float4*)(in + i);
    ushort4 o;
    o.x = f2b(v.x); o.y = f2b(v.y); o.z = f2b(v.z); o.w = f2b(v.w);
    *(ushort4*)(out + i) = o;
    if (blockIdx.x < NEDGES / 256) {
        int e = blockIdx.x * 256 + threadIdx.x;
        atomicAdd(&pad[dst[e] << 4], 1);
    }
}

__global__ __launch_bounds__(256) void cvt_w(const float* __restrict__ Wfc,
                                             const float* __restrict__ Wres,
                                             unsigned short* __restrict__ out)
{
    int i = (blockIdx.x * 256 + threadIdx.x) * 4;   // 131072 total
    float4 v = (i < 65536) ? *(const float4*)(Wfc + i)
                           : *(const float4*)(Wres + (i - 65536));
    ushort4 o;
    o.x = f2b(v.x); o.y = f2b(v.y); o.z = f2b(v.z); o.w = f2b(v.w);
    *(ushort4*)(out + i) = o;
}

// ---------------- bf16 MFMA dual GEMM + fused el/er epilogue ----------------
__global__ __launch_bounds__(256) void gemm_mfma(
    const unsigned short* __restrict__ featb,   // [N][256] bf16
    const unsigned short* __restrict__ Wb,      // [512][256] bf16
    const float* __restrict__ bias,
    const float* __restrict__ attn_l, const float* __restrict__ attn_r,
    unsigned short* __restrict__ fsb,           // [N][256] bf16
    float* __restrict__ rst,                    // [N][256] fp32
    float* __restrict__ el, float* __restrict__ er)
{
    const int b = blockIdx.x;
    const int grp = b >> 5, w32 = b & 31;
    const int bx = grp * 8 + (w32 & 7);
    const int ny = w32 >> 3;
    if (bx >= (NNODES + 127) / 128) return;

    __shared__ __align__(16) char smem[32768];
    char* sA = smem;
    char* sB = smem + 16384;

    const int tid = threadIdx.x;
    const int w = tid >> 6, l = tid & 63;
    const int wm = w & 1, wn = w >> 1;
    const int row0 = bx * 128;

    f32x4 acc[4][4];
#pragma unroll
    for (int tm = 0; tm < 4; ++tm)
#pragma unroll
        for (int tn = 0; tn < 4; ++tn) acc[tm][tn] = (f32x4)0.f;

    const int srow = tid >> 3;
    const int sslot = tid & 7;

    for (int k0 = 0; k0 < 256; k0 += 64) {
        if (k0) __syncthreads();
#pragma unroll
        for (int it = 0; it < 4; ++it) {
            int r = srow + it * 32;
            int gr = row0 + r; if (gr >= NNODES) gr = NNODES - 1;
            int kc = sslot ^ (r & 7);
            const unsigned short* g = featb + (size_t)gr * 256 + k0 + kc * 8;
            void* sp = sA + (it * 256 + w * 64) * 16;
            __builtin_amdgcn_global_load_lds((glb_cvp)g, (lds_vp)sp, 16, 0, 0);
        }
#pragma unroll
        for (int it = 0; it < 4; ++it) {
            int r = srow + it * 32;
            int kc = sslot ^ (r & 7);
            const unsigned short* g = Wb + (size_t)(ny * 128 + r) * 256 + k0 + kc * 8;
            void* sp = sB + (it * 256 + w * 64) * 16;
            __builtin_amdgcn_global_load_lds((glb_cvp)g, (lds_vp)sp, 16, 0, 0);
        }
        __syncthreads();

        const int quad = l >> 4;
#pragma unroll
        for (int kk = 0; kk < 2; ++kk) {
            const int kc = kk * 4 + quad;
            bf16x8 af[4], bq[4];
#pragma unroll
            for (int tm = 0; tm < 4; ++tm) {
                int m = wm * 64 + tm * 16 + (l & 15);
                af[tm] = *(const bf16x8*)(sA + m * 128 + ((kc ^ (m & 7)) * 16));
            }
#pragma unroll
            for (int tn = 0; tn < 4; ++tn) {
                int n = wn * 64 + tn * 16 + (l & 15);
                bq[tn] = *(const bf16x8*)(sB + n * 128 + ((kc ^ (n & 7)) * 16));
            }
#pragma unroll
            for (int tm = 0; tm < 4; ++tm)
#pragma unroll
                for (int tn = 0; tn < 4; ++tn)
                    acc[tm][tn] = __builtin_amdgcn_mfma_f32_16x16x32_bf16(
                        af[tm], bq[tn], acc[tm][tn], 0, 0, 0);
        }
    }

    const int quad = l >> 4, c15 = l & 15;
    if (ny < 2) {
        // ---- fsb stores ----
#pragma unroll
        for (int tm = 0; tm < 4; ++tm) {
            int rb = row0 + wm * 64 + tm * 16 + quad * 4;
#pragma unroll
            for (int tn = 0; tn < 4; ++tn) {
                int cg = ny * 128 + wn * 64 + tn * 16 + c15;
#pragma unroll
                for (int reg = 0; reg < 4; ++reg) {
                    int r = rb + reg;
                    if (r < NNODES) fsb[(size_t)r * 256 + cg] = f2b(acc[tm][tn][reg]);
                }
            }
        }
        // ---- fused el/er: this wave owns head hh's full 64 columns ----
        const int hh = ny * 2 + wn;
        float alv[4], arv[4];
#pragma unroll
        for (int tn = 0; tn < 4; ++tn) {
            alv[tn] = attn_l[hh * 64 + tn * 16 + c15];
            arv[tn] = attn_r[hh * 64 + tn * 16 + c15];
        }
#pragma unroll
        for (int tm = 0; tm < 4; ++tm) {
#pragma unroll
            for (int reg = 0; reg < 4; ++reg) {
                float pl = 0.f, pr = 0.f;
#pragma unroll
                for (int tn = 0; tn < 4; ++tn) {
                    float v = acc[tm][tn][reg];
                    pl = fmaf(v, alv[tn], pl);
                    pr = fmaf(v, arv[tn], pr);
                }
#pragma unroll
                for (int d = 1; d < 16; d <<= 1) {
                    pl += __shfl_xor(pl, d);
                    pr += __shfl_xor(pr, d);
                }
                if (c15 == 0) {
                    int r = row0 + wm * 64 + tm * 16 + quad * 4 + reg;
                    if (r < NNODES) {
                        el[r * NHEAD + hh] = pl;
                        er[r * NHEAD + hh] = pr;
                    }
                }
            }
        }
    } else {
#pragma unroll
        for (int tm = 0; tm < 4; ++tm) {
            int rb = row0 + wm * 64 + tm * 16 + quad * 4;
#pragma unroll
            for (int tn = 0; tn < 4; ++tn) {
                int co = (ny - 2) * 128 + wn * 64 + tn * 16 + c15;
                float b2 = bias[co];
#pragma unroll
                for (int reg = 0; reg < 4; ++reg) {
                    int r = rb + reg;
                    if (r < NNODES) rst[(size_t)r * 256 + co] = acc[tm][tn][reg] + b2;
                }
            }
        }
    }
}

// ---------------- CSR offsets + fused global el-max ----------------
// Wave-aggregated allocation (one atomic per wave); reads the padded count,
// rewrites it as the scatter cursor, stores compact deg for agg. Each block
// also max-reduces its el range and feeds gmax (replaces gmax_kernel).
__global__ __launch_bounds__(256) void offset_kernel(int* __restrict__ pad,
                                                     int* __restrict__ off,
                                                     int* __restrict__ deg,
                                                     int* __restrict__ total,
                                                     const float* __restrict__ el,
                                                     unsigned int* __restrict__ gmax)
{
    int n = blockIdx.x * 256 + threadIdx.x;
    int lane = threadIdx.x & 63;
    int c = (n < NNODES) ? pad[n << 4] : 0;
    int incl = c;
#pragma unroll
    for (int d = 1; d < 64; d <<= 1) {
        int t = __shfl_up(incl, d);
        if (lane >= d) incl += t;
    }
    int wsum = __shfl(incl, 63);
    int base = 0;
    if (lane == 0) base = atomicAdd(total, wsum);
    base = __shfl(base, 0);
    if (n < NNODES) {
        int o = base + incl - c;
        off[n] = o;
        deg[n] = c;
        pad[n << 4] = o;          // becomes the scatter cursor
    }
    // ---- fused el-max over this block's range ----
    float4 mx = make_float4(-1e30f, -1e30f, -1e30f, -1e30f);
    if (n < NNODES) {
        float4 v = *(const float4*)(el + (size_t)n * 4);
        mx = v;
    }
#pragma unroll
    for (int d = 32; d > 0; d >>= 1) {
        mx.x = fmaxf(mx.x, __shfl_xor(mx.x, d));
        mx.y = fmaxf(mx.y, __shfl_xor(mx.y, d));
        mx.z = fmaxf(mx.z, __shfl_xor(mx.z, d));
        mx.w = fmaxf(mx.w, __shfl_xor(mx.w, d));
    }
    if (lane == 0) {
        atomicMax(&gmax[0], fmap(mx.x));
        atomicMax(&gmax[1], fmap(mx.y));
        atomicMax(&gmax[2], fmap(mx.z));
        atomicMax(&gmax[3], fmap(mx.w));
    }
}

// One random 8B store per edge (edge id + src packed); cursor atomics hit
// the padded array (one per line). eperm ALIASES featb (dead after gemm).
__global__ __launch_bounds__(256) void scatter_kernel(const int* __restrict__ dst,
                                                      const int* __restrict__ src,
                                                      int* __restrict__ pad,
                                                      int2* __restrict__ eperm)
{
    int e = blockIdx.x * 256 + threadIdx.x;
    if (e < NEDGES) {
        int s = src[e];
        int p = atomicAdd(&pad[dst[e] << 4], 1);
        eperm[p] = make_int2(e, s);
    }
}

// ---------------- agg: one wave per dst node ----------------
// Softmax shift is the node-independent-per-head bound M = lrelu(gmax_el + er):
// lrelu monotone => M >= every neighbor logit; softmax shift-invariant => exact.
// eperm (edge id, src) read coalesced; sweep 2 gathers two fsb rows per step,
// dwordx4 per lane, unroll 8.
__global__ __launch_bounds__(256) void agg_kernel(
    const int2* __restrict__ eperm,
    const int* __restrict__ off, const int* __restrict__ deg_arr,
    const float* __restrict__ el, const float* __restrict__ er,
    const unsigned int* __restrict__ gmax,
    const unsigned short* __restrict__ fsb,
    float* __restrict__ rst,
    float* __restrict__ a_out)
{
    const int tid = threadIdx.x;
    const int wv = tid >> 6, lane = tid & 63;
    const int n = blockIdx.x * 4 + wv;
    const int deg = deg_arr[n];
    if (deg == 0) return;              // rst keeps residual
    const int o0 = off[n];

    __shared__ __align__(16) float a_sh[4][64][4];
    float* aw = &a_sh[wv][0][0];

    const float4 er4 = *(const float4*)(er + (size_t)n * NHEAD);
    const uint4 g4 = *(const uint4*)gmax;
    float4 M;
    M.x = lrelu(funmap(g4.x) + er4.x);
    M.y = lrelu(funmap(g4.y) + er4.y);
    M.z = lrelu(funmap(g4.z) + er4.z);
    M.w = lrelu(funmap(g4.w) + er4.w);

    // ---- sweep 1: s = sum exp(l - M) ----
    float4 s = make_float4(0.f, 0.f, 0.f, 0.f);
    int s0_save = 0, e0_save = 0;
    float4 l0_save = make_float4(0.f, 0.f, 0.f, 0.f);

    for (int base = 0; base < deg; base += 64) {
        int i = base + lane;
        bool valid = i < deg;
        int2 es = eperm[o0 + (valid ? i : deg - 1)];
        int sidx = es.y;
        float4 ev = *(const float4*)(el + (size_t)sidx * NHEAD);
        float4 l;
        l.x = lrelu(ev.x + er4.x); l.y = lrelu(ev.y + er4.y);
        l.z = lrelu(ev.z + er4.z); l.w = lrelu(ev.w + er4.w);
        if (base == 0) { s0_save = sidx; e0_save = es.x; l0_save = l; }
        s.x += valid ? __expf(l.x - M.x) : 0.f;
        s.y += valid ? __expf(l.y - M.y) : 0.f;
        s.z += valid ? __expf(l.z - M.z) : 0.f;
        s.w += valid ? __expf(l.w - M.w) : 0.f;
    }
#pragma unroll
    for (int d = 32; d > 0; d >>= 1) {
        s.x += __shfl_xor(s.x, d);
        s.y += __shfl_xor(s.y, d);
        s.z += __shfl_xor(s.z, d);
        s.w += __shfl_xor(s.w, d);
    }
    float4 inv;
    inv.x = 1.f / fmaxf(s.x, 1e-20f);
    inv.y = 1.f / fmaxf(s.y, 1e-20f);
    inv.z = 1.f / fmaxf(s.z, 1e-20f);
    inv.w = 1.f / fmaxf(s.w, 1e-20f);

    // ---- sweep 2: normalized a + two-row dwordx4 gather-accumulate ----
    const int rsel = lane >> 5;          // 0: even rows, 1: odd rows
    const int c    = lane & 31;          // 32 lanes cover one 512B row
    const int h2   = c >> 3;             // head of this lane's 8 columns
    const unsigned int coff = (unsigned)c << 4;   // byte offset in row (16B)

    float acc[8];
#pragma unroll
    for (int k = 0; k < 8; ++k) acc[k] = 0.f;

    for (int base = 0; base < deg; base += 64) {
        int i = base + lane;
        bool valid = i < deg;
        int sidx, e; float4 l;
        if (base == 0) { sidx = s0_save; e = e0_save; l = l0_save; }
        else {
            int2 es = eperm[o0 + (valid ? i : deg - 1)];
            e = es.x; sidx = es.y;
            float4 ev = *(const float4*)(el + (size_t)sidx * NHEAD);
            l.x = lrelu(ev.x + er4.x); l.y = lrelu(ev.y + er4.y);
            l.z = lrelu(ev.z + er4.z); l.w = lrelu(ev.w + er4.w);
        }
        float4 a;
        a.x = valid ? __expf(l.x - M.x) * inv.x : 0.f;
        a.y = valid ? __expf(l.y - M.y) * inv.y : 0.f;
        a.z = valid ? __expf(l.z - M.z) * inv.z : 0.f;
        a.w = valid ? __expf(l.w - M.w) * inv.w : 0.f;
        *(float4*)(aw + (lane << 2)) = a;   // wave-synchronous staging (0-padded)

        if (valid) *(float4*)(a_out + (size_t)e * NHEAD) = a;   // fused a_out

        int nc = min(64, deg - base);
#pragma unroll 8
        for (int jj = 0; jj < nc; jj += 2) {
            int sjA = __builtin_amdgcn_readlane(sidx, jj);
            int sjB = __builtin_amdgcn_readlane(sidx, jj + 1);
            float av = aw[((jj + rsel) << 2) + h2];   // 0 for padded slots
            int sj = rsel ? sjB : sjA;
            unsigned int boff = ((unsigned)sj << 9) + coff;
            uint4 p = *(const uint4*)((const char*)fsb + boff);
            acc[0] = fmaf(av, __uint_as_float(p.x << 16),         acc[0]);
            acc[1] = fmaf(av, __uint_as_float(p.x & 0xffff0000u), acc[1]);
            acc[2] = fmaf(av, __uint_as_float(p.y << 16),         acc[2]);
            acc[3] = fmaf(av, __uint_as_float(p.y & 0xffff0000u), acc[3]);
            acc[4] = fmaf(av, __uint_as_float(p.z << 16),         acc[4]);
            acc[5] = fmaf(av, __uint_as_float(p.z & 0xffff0000u), acc[5]);
            acc[6] = fmaf(av, __uint_as_float(p.w << 16),         acc[6]);
            acc[7] = fmaf(av, __uint_as_float(p.w & 0xffff0000u), acc[7]);
        }
    }
    // combine even/odd halves: partner lane (xor 32) holds same columns
#pragma unroll
    for (int k = 0; k < 8; ++k) acc[k] += __shfl_xor(acc[k], 32);
    // each lane writes 16B: rsel=0 -> cols c*8..+3, rsel=1 -> cols c*8+4..+7
    float o0v = rsel ? acc[4] : acc[0];
    float o1v = rsel ? acc[5] : acc[1];
    float o2v = rsel ? acc[6] : acc[2];
    float o3v = rsel ? acc[7] : acc[3];
    size_t ro = (size_t)n * 256 + ((size_t)c << 3) + ((size_t)rsel << 2);
    float4 r = *(float4*)(rst + ro);
    r.x += o0v; r.y += o1v; r.z += o2v; r.w += o3v;
    *(float4*)(rst + ro) = r;
}

// ---------------- launch ----------------
extern "C" void kernel_launch(void* const* d_in, const int* in_sizes, int n_in,
                              void* d_out, int out_size, void* d_ws, size_t ws_size,
                              hipStream_t stream) {
    const float* feat   = (const float*)d_in[0];
    const int*   src    = (const int*)d_in[1];
    const int*   dst    = (const int*)d_in[2];
    const float* Wfc    = (const float*)d_in[3];
    const float* attn_l = (const float*)d_in[4];
    const float* attn_r = (const float*)d_in[5];
    const float* Wres   = (const float*)d_in[6];
    const float* bias   = (const float*)d_in[7];

    float* rst   = (float*)d_out;                              // N*256
    float* a_out = (float*)d_out + (size_t)NNODES * CDIM;      // E*4

    unsigned short* featb = (unsigned short*)d_ws;             // N*256 bf16
    unsigned short* fsb   = featb + (size_t)NNODES * CDIM;     // N*256 bf16
    unsigned short* Wb    = fsb + (size_t)NNODES * CDIM;       // 512*256 bf16
    float* el      = (float*)(Wb + 512 * 256);                 // N*4
    float* er      = el + (size_t)NNODES * NHEAD;              // N*4
    unsigned int* gmax = (unsigned int*)(er + (size_t)NNODES * NHEAD); // 4
    int* total  = (int*)(gmax + 4);                            // 4
    int* deg    = total + 4;                                   // N
    int* off    = deg + NNODES;                                // N
    int* pad    = off + NNODES;                                // N*16 (64B/node)
    // eperm reuses featb's storage (featb dead after gemm_mfma; scatter and
    // agg run strictly after it each call) -> no workspace growth.
    int2* eperm = (int2*)featb;                                // E int2 (alias)

    hipMemsetAsync(gmax, 0, 8 * sizeof(int), stream);          // gmax + total
    hipMemsetAsync(pad, 0, (size_t)NNODES * 16 * sizeof(int), stream);

    cvt_feat_count<<<(NNODES * CDIM) / (256 * 4), 256, 0, stream>>>(feat, featb,
                                                                    dst, pad);
    cvt_w<<<(512 * 256) / (256 * 4), 256, 0, stream>>>(Wfc, Wres, Wb);

    // 782 row-blocks -> 98 groups of 8 -> grid 98*32 = 3136 (tail guarded)
    gemm_mfma<<<3136, 256, 0, stream>>>(featb, Wb, bias, attn_l, attn_r,
                                        fsb, rst, el, er);

    offset_kernel<<<(NNODES + 255) / 256, 256, 0, stream>>>(pad, off, deg, total,
                                                            el, gmax);
    scatter_kernel<<<(NEDGES + 255) / 256, 256, 0, stream>>>(dst, src, pad, eperm);

    agg_kernel<<<NNODES / 4, 256, 0, stream>>>(eperm, off, deg, el, er, gmax,
                                               fsb, rst, a_out);
}

// Round 9
// 676.705 us; speedup vs baseline: 1.0014x; 1.0014x over previous
//
#include <hip/hip_runtime.h>

// ---------------- problem constants ----------------
#define NNODES 100000
#define NEDGES 1600000
#define KDIM 256          // IN
#define CDIM 256          // H*F
#define NHEAD 4
#define FDIM 64
#define NEG 0.05f

typedef short bf16x8 __attribute__((ext_vector_type(8)));   // 8 bf16 in 4 VGPRs
typedef float f32x4  __attribute__((ext_vector_type(4)));
typedef __attribute__((address_space(3))) void*       lds_vp;
typedef __attribute__((address_space(1))) const void* glb_cvp;

__device__ __forceinline__ unsigned short f2b(float x) {   // fp32 -> bf16 RNE
    unsigned int u = __float_as_uint(x);
    return (unsigned short)((u + 0x7FFFu + ((u >> 16) & 1u)) >> 16);
}
__device__ __forceinline__ float b2f(unsigned short b) {
    return __uint_as_float(((unsigned int)b) << 16);
}
__device__ __forceinline__ float lrelu(float x) { return x > 0.f ? x : NEG * x; }

// monotone float<->uint mapping for atomicMax on signed floats
__device__ __forceinline__ unsigned int fmap(float f) {
    unsigned int u = __float_as_uint(f);
    return u ^ ((u >> 31) ? 0xFFFFFFFFu : 0x80000000u);
}
__device__ __forceinline__ float funmap(unsigned int u) {
    return __uint_as_float(u ^ ((u & 0x80000000u) ? 0x80000000u : 0xFFFFFFFFu));
}

// ---------------- fp32 -> bf16 convert + fused edge count ----------------
// Compact cnt (R7 showed padded counters REGRESS: line-footprint traffic
// beats slice-serialization; L2 atomics to 400KB pipeline fine).
__global__ __launch_bounds__(256) void cvt_feat_count(
    const float* __restrict__ in, unsigned short* __restrict__ out,
    const int* __restrict__ dst, int* __restrict__ cnt)
{
    int i = (blockIdx.x * 256 + threadIdx.x) * 4;
    float4 v = *(const float4*)(in + i);
    ushort4 o;
    o.x = f2b(v.x); o.y = f2b(v.y); o.z = f2b(v.z); o.w = f2b(v.w);
    *(ushort4*)(out + i) = o;
    if (blockIdx.x < NEDGES / 256) {
        int e = blockIdx.x * 256 + threadIdx.x;
        atomicAdd(&cnt[dst[e]], 1);
    }
}

__global__ __launch_bounds__(256) void cvt_w(const float* __restrict__ Wfc,
                                             const float* __restrict__ Wres,
                                             unsigned short* __restrict__ out)
{
    int i = (blockIdx.x * 256 + threadIdx.x) * 4;   // 131072 total
    float4 v = (i < 65536) ? *(const float4*)(Wfc + i)
                           : *(const float4*)(Wres + (i - 65536));
    ushort4 o;
    o.x = f2b(v.x); o.y = f2b(v.y); o.z = f2b(v.z); o.w = f2b(v.w);
    *(ushort4*)(out + i) = o;
}

// ---------------- bf16 MFMA dual GEMM + fused el/er epilogue ----------------
// OPERAND-SWAPPED: acc[tm][tn] = mfma(bq, af, acc) computes the C^T fragment,
// so per lane: output row = c15 (one row per tm), output col = quad*4+reg
// (4 CONSECUTIVE cols). Epilogue: 16x 8B fsb stores / 16x float4 rst stores
// per thread (was 64 scalar), el/er reduce = 2 shuffle levels (was 4).
__global__ __launch_bounds__(256) void gemm_mfma(
    const unsigned short* __restrict__ featb,   // [N][256] bf16
    const unsigned short* __restrict__ Wb,      // [512][256] bf16
    const float* __restrict__ bias,
    const float* __restrict__ attn_l, const float* __restrict__ attn_r,
    unsigned short* __restrict__ fsb,           // [N][256] bf16
    float* __restrict__ rst,                    // [N][256] fp32
    float* __restrict__ el, float* __restrict__ er)
{
    const int b = blockIdx.x;
    const int grp = b >> 5, w32 = b & 31;
    const int bx = grp * 8 + (w32 & 7);
    const int ny = w32 >> 3;
    if (bx >= (NNODES + 127) / 128) return;

    __shared__ __align__(16) char smem[32768];
    char* sA = smem;
    char* sB = smem + 16384;

    const int tid = threadIdx.x;
    const int w = tid >> 6, l = tid & 63;
    const int wm = w & 1, wn = w >> 1;
    const int row0 = bx * 128;

    f32x4 acc[4][4];
#pragma unroll
    for (int tm = 0; tm < 4; ++tm)
#pragma unroll
        for (int tn = 0; tn < 4; ++tn) acc[tm][tn] = (f32x4)0.f;

    const int srow = tid >> 3;
    const int sslot = tid & 7;

    for (int k0 = 0; k0 < 256; k0 += 64) {
        if (k0) __syncthreads();
#pragma unroll
        for (int it = 0; it < 4; ++it) {
            int r = srow + it * 32;
            int gr = row0 + r; if (gr >= NNODES) gr = NNODES - 1;
            int kc = sslot ^ (r & 7);
            const unsigned short* g = featb + (size_t)gr * 256 + k0 + kc * 8;
            void* sp = sA + (it * 256 + w * 64) * 16;
            __builtin_amdgcn_global_load_lds((glb_cvp)g, (lds_vp)sp, 16, 0, 0);
        }
#pragma unroll
        for (int it = 0; it < 4; ++it) {
            int r = srow + it * 32;
            int kc = sslot ^ (r & 7);
            const unsigned short* g = Wb + (size_t)(ny * 128 + r) * 256 + k0 + kc * 8;
            void* sp = sB + (it * 256 + w * 64) * 16;
            __builtin_amdgcn_global_load_lds((glb_cvp)g, (lds_vp)sp, 16, 0, 0);
        }
        __syncthreads();

        const int quad = l >> 4;
#pragma unroll
        for (int kk = 0; kk < 2; ++kk) {
            const int kc = kk * 4 + quad;
            bf16x8 af[4], bq[4];
#pragma unroll
            for (int tm = 0; tm < 4; ++tm) {
                int m = wm * 64 + tm * 16 + (l & 15);
                af[tm] = *(const bf16x8*)(sA + m * 128 + ((kc ^ (m & 7)) * 16));
            }
#pragma unroll
            for (int tn = 0; tn < 4; ++tn) {
                int n = wn * 64 + tn * 16 + (l & 15);
                bq[tn] = *(const bf16x8*)(sB + n * 128 + ((kc ^ (n & 7)) * 16));
            }
#pragma unroll
            for (int tm = 0; tm < 4; ++tm)
#pragma unroll
                for (int tn = 0; tn < 4; ++tn)
                    acc[tm][tn] = __builtin_amdgcn_mfma_f32_16x16x32_bf16(
                        bq[tn], af[tm], acc[tm][tn], 0, 0, 0);   // SWAPPED
        }
    }

    const int quad = l >> 4, c15 = l & 15;
    if (ny < 2) {
        const int hh = ny * 2 + wn;
        // per-lane attn slices: cols tn*16 + quad*4 + {0..3} of head hh
        float4 alv[4], arv[4];
#pragma unroll
        for (int tn = 0; tn < 4; ++tn) {
            alv[tn] = *(const float4*)(attn_l + hh * 64 + tn * 16 + quad * 4);
            arv[tn] = *(const float4*)(attn_r + hh * 64 + tn * 16 + quad * 4);
        }
#pragma unroll
        for (int tm = 0; tm < 4; ++tm) {
            int row = row0 + wm * 64 + tm * 16 + c15;
            bool ok = row < NNODES;
            // ---- fsb: 4 packed 8B stores ----
#pragma unroll
            for (int tn = 0; tn < 4; ++tn) {
                int cb = ny * 128 + wn * 64 + tn * 16 + quad * 4;
                unsigned int lo = (unsigned int)f2b(acc[tm][tn][0])
                                | ((unsigned int)f2b(acc[tm][tn][1]) << 16);
                unsigned int hi = (unsigned int)f2b(acc[tm][tn][2])
                                | ((unsigned int)f2b(acc[tm][tn][3]) << 16);
                if (ok) *(uint2*)(fsb + (size_t)row * 256 + cb) = make_uint2(lo, hi);
            }
            // ---- el/er: 16 fmaf + 2-level quad reduce ----
            float pl = 0.f, pr = 0.f;
#pragma unroll
            for (int tn = 0; tn < 4; ++tn) {
#pragma unroll
                for (int reg = 0; reg < 4; ++reg) {
                    float v = acc[tm][tn][reg];
                    pl = fmaf(v, ((const float*)&alv[tn])[reg], pl);
                    pr = fmaf(v, ((const float*)&arv[tn])[reg], pr);
                }
            }
            pl += __shfl_xor(pl, 16); pl += __shfl_xor(pl, 32);
            pr += __shfl_xor(pr, 16); pr += __shfl_xor(pr, 32);
            if (quad == 0 && ok) {
                el[row * NHEAD + hh] = pl;
                er[row * NHEAD + hh] = pr;
            }
        }
    } else {
        float4 b4[4];
#pragma unroll
        for (int tn = 0; tn < 4; ++tn)
            b4[tn] = *(const float4*)(bias + (ny - 2) * 128 + wn * 64 + tn * 16 + quad * 4);
#pragma unroll
        for (int tm = 0; tm < 4; ++tm) {
            int row = row0 + wm * 64 + tm * 16 + c15;
            if (row >= NNODES) continue;
#pragma unroll
            for (int tn = 0; tn < 4; ++tn) {
                int cb = (ny - 2) * 128 + wn * 64 + tn * 16 + quad * 4;
                float4 o;
                o.x = acc[tm][tn][0] + b4[tn].x;
                o.y = acc[tm][tn][1] + b4[tn].y;
                o.z = acc[tm][tn][2] + b4[tn].z;
                o.w = acc[tm][tn][3] + b4[tn].w;
                *(float4*)(rst + (size_t)row * 256 + cb) = o;
            }
        }
    }
}

// ---------------- CSR offsets + fused global el-max ----------------
// Wave-aggregated allocation (one atomic per wave); also block-max-reduces
// el and feeds gmax (no separate gmax kernel).
__global__ __launch_bounds__(256) void offset_kernel(const int* __restrict__ cnt,
                                                     int* __restrict__ off,
                                                     int* __restrict__ cursor,
                                                     int* __restrict__ total,
                                                     const float* __restrict__ el,
                                                     unsigned int* __restrict__ gmax)
{
    int n = blockIdx.x * 256 + threadIdx.x;
    int lane = threadIdx.x & 63;
    int c = (n < NNODES) ? cnt[n] : 0;
    int incl = c;
#pragma unroll
    for (int d = 1; d < 64; d <<= 1) {
        int t = __shfl_up(incl, d);
        if (lane >= d) incl += t;
    }
    int wsum = __shfl(incl, 63);
    int base = 0;
    if (lane == 0) base = atomicAdd(total, wsum);
    base = __shfl(base, 0);
    if (n < NNODES) {
        int o = base + incl - c;
        off[n] = o;
        cursor[n] = o;
    }
    // ---- fused el-max over this block's range ----
    float4 mx = make_float4(-1e30f, -1e30f, -1e30f, -1e30f);
    if (n < NNODES) mx = *(const float4*)(el + (size_t)n * 4);
#pragma unroll
    for (int d = 32; d > 0; d >>= 1) {
        mx.x = fmaxf(mx.x, __shfl_xor(mx.x, d));
        mx.y = fmaxf(mx.y, __shfl_xor(mx.y, d));
        mx.z = fmaxf(mx.z, __shfl_xor(mx.z, d));
        mx.w = fmaxf(mx.w, __shfl_xor(mx.w, d));
    }
    if (lane == 0) {
        atomicMax(&gmax[0], fmap(mx.x));
        atomicMax(&gmax[1], fmap(mx.y));
        atomicMax(&gmax[2], fmap(mx.z));
        atomicMax(&gmax[3], fmap(mx.w));
    }
}

// One random 8B store per edge (edge id + src packed). eperm ALIASES featb
// (dead after gemm_mfma, stream-ordered).
__global__ __launch_bounds__(256) void scatter_kernel(const int* __restrict__ dst,
                                                      const int* __restrict__ src,
                                                      int* __restrict__ cursor,
                                                      int2* __restrict__ eperm)
{
    int e = blockIdx.x * 256 + threadIdx.x;
    if (e < NEDGES) {
        int s = src[e];
        int p = atomicAdd(&cursor[dst[e]], 1);
        eperm[p] = make_int2(e, s);
    }
}

// ---------------- agg: one wave per dst node ----------------
// Softmax shift is the node-independent-per-head bound M = lrelu(gmax_el + er):
// lrelu monotone => M >= every neighbor logit; softmax shift-invariant => exact.
// eperm (edge id, src) read coalesced; sweep 2 gathers two fsb rows per step,
// dwordx4 per lane, unroll 8.
__global__ __launch_bounds__(256) void agg_kernel(
    const int2* __restrict__ eperm,
    const int* __restrict__ off, const int* __restrict__ cnt,
    const float* __restrict__ el, const float* __restrict__ er,
    const unsigned int* __restrict__ gmax,
    const unsigned short* __restrict__ fsb,
    float* __restrict__ rst,
    float* __restrict__ a_out)
{
    const int tid = threadIdx.x;
    const int wv = tid >> 6, lane = tid & 63;
    const int n = blockIdx.x * 4 + wv;
    const int deg = cnt[n];
    if (deg == 0) return;              // rst keeps residual
    const int o0 = off[n];

    __shared__ __align__(16) float a_sh[4][64][4];
    float* aw = &a_sh[wv][0][0];

    const float4 er4 = *(const float4*)(er + (size_t)n * NHEAD);
    const uint4 g4 = *(const uint4*)gmax;
    float4 M;
    M.x = lrelu(funmap(g4.x) + er4.x);
    M.y = lrelu(funmap(g4.y) + er4.y);
    M.z = lrelu(funmap(g4.z) + er4.z);
    M.w = lrelu(funmap(g4.w) + er4.w);

    // ---- sweep 1: s = sum exp(l - M) ----
    float4 s = make_float4(0.f, 0.f, 0.f, 0.f);
    int s0_save = 0, e0_save = 0;
    float4 l0_save = make_float4(0.f, 0.f, 0.f, 0.f);

    for (int base = 0; base < deg; base += 64) {
        int i = base + lane;
        bool valid = i < deg;
        int2 es = eperm[o0 + (valid ? i : deg - 1)];
        int sidx = es.y;
        float4 ev = *(const float4*)(el + (size_t)sidx * NHEAD);
        float4 l;
        l.x = lrelu(ev.x + er4.x); l.y = lrelu(ev.y + er4.y);
        l.z = lrelu(ev.z + er4.z); l.w = lrelu(ev.w + er4.w);
        if (base == 0) { s0_save = sidx; e0_save = es.x; l0_save = l; }
        s.x += valid ? __expf(l.x - M.x) : 0.f;
        s.y += valid ? __expf(l.y - M.y) : 0.f;
        s.z += valid ? __expf(l.z - M.z) : 0.f;
        s.w += valid ? __expf(l.w - M.w) : 0.f;
    }
#pragma unroll
    for (int d = 32; d > 0; d >>= 1) {
        s.x += __shfl_xor(s.x, d);
        s.y += __shfl_xor(s.y, d);
        s.z += __shfl_xor(s.z, d);
        s.w += __shfl_xor(s.w, d);
    }
    float4 inv;
    inv.x = 1.f / fmaxf(s.x, 1e-20f);
    inv.y = 1.f / fmaxf(s.y, 1e-20f);
    inv.z = 1.f / fmaxf(s.z, 1e-20f);
    inv.w = 1.f / fmaxf(s.w, 1e-20f);

    // ---- sweep 2: normalized a + two-row dwordx4 gather-accumulate ----
    const int rsel = lane >> 5;          // 0: even rows, 1: odd rows
    const int c    = lane & 31;          // 32 lanes cover one 512B row
    const int h2   = c >> 3;             // head of this lane's 8 columns
    const unsigned int coff = (unsigned)c << 4;   // byte offset in row (16B)

    float acc[8];
#pragma unroll
    for (int k = 0; k < 8; ++k) acc[k] = 0.f;

    for (int base = 0; base < deg; base += 64) {
        int i = base + lane;
        bool valid = i < deg;
        int sidx, e; float4 l;
        if (base == 0) { sidx = s0_save; e = e0_save; l = l0_save; }
        else {
            int2 es = eperm[o0 + (valid ? i : deg - 1)];
            e = es.x; sidx = es.y;
            float4 ev = *(const float4*)(el + (size_t)sidx * NHEAD);
            l.x = lrelu(ev.x + er4.x); l.y = lrelu(ev.y + er4.y);
            l.z = lrelu(ev.z + er4.z); l.w = lrelu(ev.w + er4.w);
        }
        float4 a;
        a.x = valid ? __expf(l.x - M.x) * inv.x : 0.f;
        a.y = valid ? __expf(l.y - M.y) * inv.y : 0.f;
        a.z = valid ? __expf(l.z - M.z) * inv.z : 0.f;
        a.w = valid ? __expf(l.w - M.w) * inv.w : 0.f;
        *(float4*)(aw + (lane << 2)) = a;   // wave-synchronous staging (0-padded)

        if (valid) *(float4*)(a_out + (size_t)e * NHEAD) = a;   // fused a_out

        int nc = min(64, deg - base);
#pragma unroll 8
        for (int jj = 0; jj < nc; jj += 2) {
            int sjA = __builtin_amdgcn_readlane(sidx, jj);
            int sjB = __builtin_amdgcn_readlane(sidx, jj + 1);
            float av = aw[((jj + rsel) << 2) + h2];   // 0 for padded slots
            int sj = rsel ? sjB : sjA;
            unsigned int boff = ((unsigned)sj << 9) + coff;
            uint4 p = *(const uint4*)((const char*)fsb + boff);
            acc[0] = fmaf(av, __uint_as_float(p.x << 16),         acc[0]);
            acc[1] = fmaf(av, __uint_as_float(p.x & 0xffff0000u), acc[1]);
            acc[2] = fmaf(av, __uint_as_float(p.y << 16),         acc[2]);
            acc[3] = fmaf(av, __uint_as_float(p.y & 0xffff0000u), acc[3]);
            acc[4] = fmaf(av, __uint_as_float(p.z << 16),         acc[4]);
            acc[5] = fmaf(av, __uint_as_float(p.z & 0xffff0000u), acc[5]);
            acc[6] = fmaf(av, __uint_as_float(p.w << 16),         acc[6]);
            acc[7] = fmaf(av, __uint_as_float(p.w & 0xffff0000u), acc[7]);
        }
    }
    // combine even/odd halves: partner lane (xor 32) holds same columns
#pragma unroll
    for (int k = 0; k < 8; ++k) acc[k] += __shfl_xor(acc[k], 32);
    // each lane writes 16B: rsel=0 -> cols c*8..+3, rsel=1 -> cols c*8+4..+7
    float o0v = rsel ? acc[4] : acc[0];
    float o1v = rsel ? acc[5] : acc[1];
    float o2v = rsel ? acc[6] : acc[2];
    float o3v = rsel ? acc[7] : acc[3];
    size_t ro = (size_t)n * 256 + ((size_t)c << 3) + ((size_t)rsel << 2);
    float4 r = *(float4*)(rst + ro);
    r.x += o0v; r.y += o1v; r.z += o2v; r.w += o3v;
    *(float4*)(rst + ro) = r;
}

// ---------------- launch ----------------
extern "C" void kernel_launch(void* const* d_in, const int* in_sizes, int n_in,
                              void* d_out, int out_size, void* d_ws, size_t ws_size,
                              hipStream_t stream) {
    const float* feat   = (const float*)d_in[0];
    const int*   src    = (const int*)d_in[1];
    const int*   dst    = (const int*)d_in[2];
    const float* Wfc    = (const float*)d_in[3];
    const float* attn_l = (const float*)d_in[4];
    const float* attn_r = (const float*)d_in[5];
    const float* Wres   = (const float*)d_in[6];
    const float* bias   = (const float*)d_in[7];

    float* rst   = (float*)d_out;                              // N*256
    float* a_out = (float*)d_out + (size_t)NNODES * CDIM;      // E*4

    unsigned short* featb = (unsigned short*)d_ws;             // N*256 bf16
    unsigned short* fsb   = featb + (size_t)NNODES * CDIM;     // N*256 bf16
    unsigned short* Wb    = fsb + (size_t)NNODES * CDIM;       // 512*256 bf16
    float* el      = (float*)(Wb + 512 * 256);                 // N*4
    float* er      = el + (size_t)NNODES * NHEAD;              // N*4
    unsigned int* gmax = (unsigned int*)(er + (size_t)NNODES * NHEAD); // 4
    int* total  = (int*)(gmax + 4);                            // 4
    int* cnt    = total + 4;                                   // N
    int* off    = cnt + NNODES;                                // N
    int* cursor = off + NNODES;                                // N
    // eperm reuses featb's storage (featb dead after gemm_mfma; scatter and
    // agg run strictly after it each call) -> no workspace growth.
    int2* eperm = (int2*)featb;                                // E int2 (alias)

    hipMemsetAsync(gmax, 0, 8 * sizeof(int), stream);          // gmax + total
    hipMemsetAsync(cnt, 0, NNODES * sizeof(int), stream);

    cvt_feat_count<<<(NNODES * CDIM) / (256 * 4), 256, 0, stream>>>(feat, featb,
                                                                    dst, cnt);
    cvt_w<<<(512 * 256) / (256 * 4), 256, 0, stream>>>(Wfc, Wres, Wb);

    // 782 row-blocks -> 98 groups of 8 -> grid 98*32 = 3136 (tail guarded)
    gemm_mfma<<<3136, 256, 0, stream>>>(featb, Wb, bias, attn_l, attn_r,
                                        fsb, rst, el, er);

    offset_kernel<<<(NNODES + 255) / 256, 256, 0, stream>>>(cnt, off, cursor,
                                                            total, el, gmax);
    scatter_kernel<<<(NEDGES + 255) / 256, 256, 0, stream>>>(dst, src, cursor,
                                                             eperm);

    agg_kernel<<<NNODES / 4, 256, 0, stream>>>(eperm, off, cnt, el, er, gmax,
                                               fsb, rst, a_out);
}